// Round 5
// baseline (1068.298 us; speedup 1.0000x reference)
//
#include <hip/hip_runtime.h>
#include <hip/hip_bf16.h>

// RandomProjectionQuantizer: proj = x @ P (4096->16), L2-normalize rows,
// argmin_k ||xn - c_k||^2  ==  argmax_k (xn . c_k - 0.5*||c_k||^2)
//
// Layout: lane = row (64 rows/wave), 4 waves/block = d-split (stage 1) and
// code-split (stage 2). P/C/h are wave-uniform -> scalar loads.
// Stage-1 accumulates in f64 (P pre-converted); stage-2 fp32 with top-2
// tracking + f64 re-check on near-ties (gap < 1e-3).

#define NROWS 32768
#define DIM   4096
#define NE    16
#define NK    4096

__device__ double P64g[DIM * NE];   // projection matrix in f64
__device__ float  hg[NK];           // 0.5*||c_k||^2

__global__ __launch_bounds__(256) void rpq_pre(const float* __restrict__ P,
                                               const float* __restrict__ C) {
    int t = blockIdx.x * 256 + threadIdx.x;   // grid = 256 blocks -> 65536 threads
    P64g[t] = (double)P[t];
    if (t < NK) {
        double s = 0.0;
        #pragma unroll
        for (int e = 0; e < NE; ++e) {
            double c = (double)C[t * NE + e];
            s = fma(c, c, s);
        }
        hg[t] = (float)(0.5 * s);
    }
}

__global__ __launch_bounds__(256) void rpq_main(const float* __restrict__ x,
                                                const float* __restrict__ Cb,
                                                int* __restrict__ out) {
    // LDS: reused across phases.
    //  phase 1: float xs[4][64][65]           = 66560 B  (x staging, pad->no conflicts)
    //  phase 2: double red[4][64][17]         = 34816 B  (cross-wave f64 reduce)
    //  phase 3: float mv[4][64][2] @0, int mi[4][64][2] @4096  (top-2 merge)
    __shared__ __align__(16) char smem[66560];
    float*  xs  = (float*)smem;
    double* red = (double*)smem;
    float*  mv  = (float*)smem;
    int*    mi  = (int*)(smem + 4096);

    const int t    = threadIdx.x;
    const int lane = t & 63;
    const int w    = __builtin_amdgcn_readfirstlane(t >> 6);  // wave id, force SGPR
    const int row0 = blockIdx.x << 6;                          // 64 rows per block

    double acc[NE];
    #pragma unroll
    for (int e = 0; e < NE; ++e) acc[e] = 0.0;

    // ---- Stage 1: proj = x @ P, f64 accumulate. Wave w owns d in [w*1024, w*1024+1024).
    // 16 chunks of 64 d's per wave; each chunk staged through LDS.
    for (int i = 0; i < 16; ++i) {
        __syncthreads();
        // stage: 4 waves' sub-chunks = 4*64rows*64d floats = 4096 float4, 16/thread
        #pragma unroll
        for (int s = 0; s < 16; ++s) {
            int f   = t + s * 256;
            int fw  = f >> 10;        // which wave's sub-chunk
            int fr  = (f >> 4) & 63;  // row within group
            int fd4 = f & 15;         // float4 within 64 floats
            float4 v = *(const float4*)(x + ((size_t)(row0 + fr) << 12) +
                                        (fw << 10) + (i << 6) + (fd4 << 2));
            float* dst = xs + (fw * 64 + fr) * 65 + fd4 * 4;
            dst[0] = v.x; dst[1] = v.y; dst[2] = v.z; dst[3] = v.w;
        }
        __syncthreads();
        // compute: lane reads its row's column (stride 65 dwords -> 2-way = free)
        const double* Pd   = P64g + (size_t)((w << 10) + (i << 6)) * NE;
        const float*  xrow = xs + (w * 64 + lane) * 65;
        #pragma unroll 4
        for (int dd = 0; dd < 64; ++dd) {
            double xv = (double)xrow[dd];
            const double* p = Pd + dd * NE;   // wave-uniform -> s_load
            #pragma unroll
            for (int e = 0; e < NE; ++e) acc[e] = fma(xv, p[e], acc[e]);
        }
    }

    // ---- cross-wave reduce (f64) ----
    __syncthreads();
    {
        double* r = red + (w * 64 + lane) * 17;
        #pragma unroll
        for (int e = 0; e < NE; ++e) r[e] = acc[e];
    }
    __syncthreads();

    double proj[NE];
    #pragma unroll
    for (int e = 0; e < NE; ++e)
        proj[e] = red[(0 * 64 + lane) * 17 + e] + red[(1 * 64 + lane) * 17 + e] +
                  red[(2 * 64 + lane) * 17 + e] + red[(3 * 64 + lane) * 17 + e];

    // ---- normalize (f64, eps semantics: x / max(||x||, 1e-12)) ----
    double s2 = 0.0;
    #pragma unroll
    for (int e = 0; e < NE; ++e) s2 = fma(proj[e], proj[e], s2);
    double nrm = sqrt(s2);
    nrm = nrm > 1e-12 ? nrm : 1e-12;
    double inv = 1.0 / nrm;
    float xn[NE];
    #pragma unroll
    for (int e = 0; e < NE; ++e) xn[e] = (float)(proj[e] * inv);

    // ---- Stage 2: wave w scans codes [w*1024, w*1024+1024), top-2 tracking ----
    const int k0 = w << 10;
    float b1 = -3.0e38f, b2 = -3.0e38f;
    int   i1 = 0, i2 = 0;
    #pragma unroll 2
    for (int j = 0; j < 1024; ++j) {
        const int k = k0 + j;
        const float* c = Cb + ((size_t)k << 4);   // wave-uniform -> s_load
        float va = -hg[k];
        float vb = 0.0f;
        #pragma unroll
        for (int e = 0; e < NE; e += 2) {
            va = fmaf(xn[e],     c[e],     va);
            vb = fmaf(xn[e + 1], c[e + 1], vb);
        }
        float v = va + vb;
        bool g1 = v > b1;
        bool g2 = v > b2;
        i2 = g1 ? i1 : (g2 ? k : i2);
        b2 = g1 ? b1 : (g2 ? v : b2);
        i1 = g1 ? k : i1;
        b1 = g1 ? v : b1;
    }

    // ---- merge 4 waves' top-2, f64 re-check near-ties, write ----
    __syncthreads();
    mv[(w * 64 + lane) * 2 + 0] = b1;
    mv[(w * 64 + lane) * 2 + 1] = b2;
    mi[(w * 64 + lane) * 2 + 0] = i1;
    mi[(w * 64 + lane) * 2 + 1] = i2;
    __syncthreads();

    if (w == 0) {
        float B1 = -3.0e38f, B2 = -3.0e38f;
        int   I1 = 0, I2 = 0;
        #pragma unroll
        for (int q = 0; q < 8; ++q) {
            float v   = mv[((q >> 1) * 64 + lane) * 2 + (q & 1)];
            int   idx = mi[((q >> 1) * 64 + lane) * 2 + (q & 1)];
            bool better = (v > B1) || (v == B1 && idx < I1);
            if (better) { B2 = B1; I2 = I1; B1 = v; I1 = idx; }
            else if ((v > B2) || (v == B2 && idx < I2)) { B2 = v; I2 = idx; }
        }
        int result = I1;
        if (B1 - B2 < 1e-3f) {   // near-tie: decide in f64 (exact at this scale)
            double v1, v2;
            {
                const float* c = Cb + ((size_t)I1 << 4);
                double dot = 0.0, n2 = 0.0;
                #pragma unroll
                for (int e = 0; e < NE; ++e) {
                    double ce = (double)c[e];
                    dot = fma((double)xn[e], ce, dot);
                    n2  = fma(ce, ce, n2);
                }
                v1 = dot - 0.5 * n2;
            }
            {
                const float* c = Cb + ((size_t)I2 << 4);
                double dot = 0.0, n2 = 0.0;
                #pragma unroll
                for (int e = 0; e < NE; ++e) {
                    double ce = (double)c[e];
                    dot = fma((double)xn[e], ce, dot);
                    n2  = fma(ce, ce, n2);
                }
                v2 = dot - 0.5 * n2;
            }
            if ((v2 > v1) || (v2 == v1 && I2 < I1)) result = I2;
        }
        out[row0 + lane] = result;
    }
}

extern "C" void kernel_launch(void* const* d_in, const int* in_sizes, int n_in,
                              void* d_out, int out_size, void* d_ws, size_t ws_size,
                              hipStream_t stream) {
    (void)in_sizes; (void)n_in; (void)d_ws; (void)ws_size; (void)out_size;
    const float* x = (const float*)d_in[0];
    const float* P = (const float*)d_in[1];
    const float* C = (const float*)d_in[2];
    int* out = (int*)d_out;

    hipLaunchKernelGGL(rpq_pre,  dim3(256), dim3(256), 0, stream, P, C);
    hipLaunchKernelGGL(rpq_main, dim3(512), dim3(256), 0, stream, x, C, out);
}